// Round 2
// baseline (649.946 us; speedup 1.0000x reference)
//
#include <hip/hip_runtime.h>

// UpBlock: deconv(8-oct GEMM) -> BN+ELU -> 27-tap gather conv -> BN+ELU
// bf16 MFMA 16x16x32 pipeline; BN stats via binned f32 atomics.
// R2: conv kernel software-pipelined (gather prefetch 1 tap ahead).

#define N_PARENT 65536
#define C_IN     128
#define C_OUT    64
#define N_CHILD  (N_PARENT * 8)
#define TAPS     27
#define NBINS    64

typedef __bf16 bf16x8 __attribute__((ext_vector_type(8)));
typedef float  f32x4  __attribute__((ext_vector_type(4)));

// workspace layout (bytes)
#define Y_OFF     0u               // bf16 y [N_CHILD][64]  = 67108864
#define WTUP_OFF  67108864u        // bf16 WtUp [8][64 n][128 k] = 131072
#define WTCV_OFF  67239936u        // bf16 WtCv [27][64 n][64 k] = 221184
#define S1_OFF    67461120u        // f32 bins1 [64][128]   = 32768
#define S2_OFF    67493888u        // f32 bins2 [64][128]   = 32768
#define AB1_OFF   67526656u        // f32 a1[64], b1[64]    = 512
#define AB2_OFF   67527168u        // f32 a2[64], b2[64]    = 512

__device__ __forceinline__ float elu_f(float f) {
    return f > 0.f ? f : (__expf(f) - 1.f);
}

// ---- prep: transpose weights to [n][k] layout, cast to bf16 ----
__global__ __launch_bounds__(256) void prep_w(const float* __restrict__ wup,
                                              const float* __restrict__ wcv,
                                              __bf16* __restrict__ wtup,
                                              __bf16* __restrict__ wtcv) {
    int i = blockIdx.x * 256 + threadIdx.x;
    if (i < 8 * 64 * 128) {
        int o = i >> 13, rem = i & 8191, n = rem >> 7, k = rem & 127;
        wtup[i] = (__bf16)wup[o * 8192 + k * 64 + n];
    } else {
        int j = i - 65536;                     // j < 27*64*64 = 110592
        int t = j >> 12, rem = j & 4095, n = rem >> 6, k = rem & 63;
        wtcv[j] = (__bf16)wcv[t * 4096 + k * 64 + n];
    }
}

// ---- kernel A: y[8p+oct] = x[p] @ W_up[oct], accumulate BN1 stats ----
__global__ __launch_bounds__(256) void deconv_bn_stats(
    const float* __restrict__ x, const __bf16* __restrict__ wtup,
    __bf16* __restrict__ y, float* __restrict__ bins) {
    __shared__ float ssum[64], ssq[64];
    int tid = threadIdx.x;
    int wave = tid >> 6, lane = tid & 63, lr = lane & 15, lg = lane >> 4;
    int p0 = blockIdx.x * 16;

    if (tid < 64) { ssum[tid] = 0.f; ssq[tid] = 0.f; }

    const float* xrow = x + (size_t)(p0 + lr) * C_IN;
    bf16x8 afr[4];
#pragma unroll
    for (int ks = 0; ks < 4; ++ks) {
        const float* src = xrow + ks * 32 + lg * 8;
        f32x4 u0 = *(const f32x4*)(src);
        f32x4 u1 = *(const f32x4*)(src + 4);
        bf16x8 a;
#pragma unroll
        for (int i = 0; i < 4; ++i) { a[i] = (__bf16)u0[i]; a[4 + i] = (__bf16)u1[i]; }
        afr[ks] = a;
    }

    float lsum[4] = {0.f, 0.f, 0.f, 0.f}, lsq[4] = {0.f, 0.f, 0.f, 0.f};
#pragma unroll
    for (int oo = 0; oo < 2; ++oo) {
        int oct = wave * 2 + oo;
#pragma unroll
        for (int nt = 0; nt < 4; ++nt) {
            f32x4 acc = {0.f, 0.f, 0.f, 0.f};
#pragma unroll
            for (int ks = 0; ks < 4; ++ks) {
                const __bf16* bp = wtup + ((size_t)(oct * 64 + nt * 16 + lr) * C_IN + ks * 32 + lg * 8);
                bf16x8 b = *(const bf16x8*)bp;
                acc = __builtin_amdgcn_mfma_f32_16x16x32_bf16(afr[ks], b, acc, 0, 0, 0);
            }
#pragma unroll
            for (int r = 0; r < 4; ++r) {
                int parent = p0 + lg * 4 + r;
                int child = parent * 8 + oct;
                float v = acc[r];
                y[(size_t)child * C_OUT + nt * 16 + lr] = (__bf16)v;
                lsum[nt] += v; lsq[nt] += v * v;
            }
        }
    }
    __syncthreads();
#pragma unroll
    for (int nt = 0; nt < 4; ++nt) {
        atomicAdd(&ssum[nt * 16 + lr], lsum[nt]);
        atomicAdd(&ssq[nt * 16 + lr], lsq[nt]);
    }
    __syncthreads();
    if (tid < 64) {
        float* b = bins + (size_t)(blockIdx.x & (NBINS - 1)) * 128;
        atomicAdd(&b[tid], ssum[tid]);
        atomicAdd(&b[64 + tid], ssq[tid]);
    }
}

// ---- finalize: per-channel a = gamma*rstd, b = beta - mu*a ----
__global__ void finalize_stats(const float* __restrict__ bins,
                               const float* __restrict__ gamma,
                               const float* __restrict__ beta,
                               float* __restrict__ ab, float invN) {
    int c = threadIdx.x;  // 64 threads
    float s = 0.f, q = 0.f;
    for (int b = 0; b < NBINS; ++b) { s += bins[b * 128 + c]; q += bins[b * 128 + 64 + c]; }
    float mu = s * invN;
    float var = q * invN - mu * mu;
    float rstd = rsqrtf(var + 1e-5f);
    float a = gamma[c] * rstd;
    ab[c] = a;
    ab[64 + c] = beta[c] - mu * a;
}

// ---- BN1 + ELU applied in place on bf16 y ----
__global__ __launch_bounds__(256) void bn_elu_y(__bf16* __restrict__ y,
                                                const float* __restrict__ ab) {
    int tid = blockIdx.x * 256 + threadIdx.x;
    int c0 = (tid * 8) & 63;
    float av[8], bv[8];
#pragma unroll
    for (int j = 0; j < 8; ++j) { av[j] = ab[c0 + j]; bv[j] = ab[64 + c0 + j]; }
#pragma unroll
    for (int t = 0; t < 4; ++t) {
        size_t e = ((size_t)t * 1048576 + tid) * 8;
        bf16x8 v = *(const bf16x8*)(y + e);
        bf16x8 o;
#pragma unroll
        for (int j = 0; j < 8; ++j) {
            float f = (float)v[j] * av[j] + bv[j];
            o[j] = (__bf16)elu_f(f);
        }
        *(bf16x8*)(y + e) = o;
    }
}

// ---- kernel C: 27-tap gather conv, software-pipelined ----
// block: 256 thr (4 waves); each wave owns 64 rows x 64 cols.
// A-gathers for tap k+1 issued right after tap k's MFMAs free the regs.
__global__ __launch_bounds__(256, 4) void conv_bn_stats(
    const __bf16* __restrict__ y, const int* __restrict__ neigh,
    const __bf16* __restrict__ wtcv, float* __restrict__ out,
    float* __restrict__ bins) {
    __shared__ float ssum[64], ssq[64];
    int tid = threadIdx.x;
    int wave = tid >> 6, lane = tid & 63, lr = lane & 15, lg = lane >> 4;
    int base = blockIdx.x * 256 + wave * 64;

    if (tid < 64) { ssum[tid] = 0.f; ssq[tid] = 0.f; }

    f32x4 acc[4][4];
#pragma unroll
    for (int mt = 0; mt < 4; ++mt)
#pragma unroll
        for (int nt = 0; nt < 4; ++nt) acc[mt][nt] = (f32x4){0.f, 0.f, 0.f, 0.f};

    // per-lane neighbor-row base pointers (row fixed per mt, tap varies)
    const int* nptr0 = neigh + (size_t)(base + 0 * 16 + lr) * TAPS;
    const int* nptr1 = neigh + (size_t)(base + 1 * 16 + lr) * TAPS;
    const int* nptr2 = neigh + (size_t)(base + 2 * 16 + lr) * TAPS;
    const int* nptr3 = neigh + (size_t)(base + 3 * 16 + lr) * TAPS;

    const __bf16* ybase = y + (size_t)lg * 8;   // lane's k-chunk offset

    int idx_c[4], idx_n[4];
    idx_c[0] = nptr0[0]; idx_c[1] = nptr1[0]; idx_c[2] = nptr2[0]; idx_c[3] = nptr3[0];
    idx_n[0] = nptr0[1]; idx_n[1] = nptr1[1]; idx_n[2] = nptr2[1]; idx_n[3] = nptr3[1];

    // tap-0 A fragments (two K-halves)
    bf16x8 a0[4], a1[4];
#pragma unroll
    for (int mt = 0; mt < 4; ++mt) a0[mt] = *(const bf16x8*)(ybase + (size_t)idx_c[mt] * 64);
#pragma unroll
    for (int mt = 0; mt < 4; ++mt) a1[mt] = *(const bf16x8*)(ybase + (size_t)idx_c[mt] * 64 + 32);

    for (int k = 0; k < TAPS; ++k) {
        const __bf16* wk = wtcv + (size_t)k * 4096 + lr * 64 + lg * 8;
        // ---- K-half 0 ----
#pragma unroll
        for (int nt = 0; nt < 4; ++nt) {
            bf16x8 b = *(const bf16x8*)(wk + nt * 1024);
#pragma unroll
            for (int mt = 0; mt < 4; ++mt)
                acc[mt][nt] = __builtin_amdgcn_mfma_f32_16x16x32_bf16(a0[mt], b, acc[mt][nt], 0, 0, 0);
        }
        // issue next-tap K-half-0 gathers into a0 (WAR: regs just consumed)
        if (k < TAPS - 1) {
#pragma unroll
            for (int mt = 0; mt < 4; ++mt)
                a0[mt] = *(const bf16x8*)(ybase + (size_t)idx_n[mt] * 64);
        }
        // ---- K-half 1 ----
#pragma unroll
        for (int nt = 0; nt < 4; ++nt) {
            bf16x8 b = *(const bf16x8*)(wk + nt * 1024 + 32);
#pragma unroll
            for (int mt = 0; mt < 4; ++mt)
                acc[mt][nt] = __builtin_amdgcn_mfma_f32_16x16x32_bf16(a1[mt], b, acc[mt][nt], 0, 0, 0);
        }
        if (k < TAPS - 1) {
#pragma unroll
            for (int mt = 0; mt < 4; ++mt)
                a1[mt] = *(const bf16x8*)(ybase + (size_t)idx_n[mt] * 64 + 32);
            if (k < TAPS - 2) {
                idx_n[0] = nptr0[k + 2]; idx_n[1] = nptr1[k + 2];
                idx_n[2] = nptr2[k + 2]; idx_n[3] = nptr3[k + 2];
            }
        }
    }

    float lsum[4] = {0.f, 0.f, 0.f, 0.f}, lsq[4] = {0.f, 0.f, 0.f, 0.f};
#pragma unroll
    for (int mt = 0; mt < 4; ++mt)
#pragma unroll
        for (int nt = 0; nt < 4; ++nt)
#pragma unroll
            for (int r = 0; r < 4; ++r) {
                float v = acc[mt][nt][r];
                int row = base + mt * 16 + lg * 4 + r;
                out[(size_t)row * C_OUT + nt * 16 + lr] = v;
                lsum[nt] += v; lsq[nt] += v * v;
            }
    __syncthreads();
#pragma unroll
    for (int nt = 0; nt < 4; ++nt) {
        atomicAdd(&ssum[nt * 16 + lr], lsum[nt]);
        atomicAdd(&ssq[nt * 16 + lr], lsq[nt]);
    }
    __syncthreads();
    if (tid < 64) {
        float* b = bins + (size_t)(blockIdx.x & (NBINS - 1)) * 128;
        atomicAdd(&b[tid], ssum[tid]);
        atomicAdd(&b[64 + tid], ssq[tid]);
    }
}

// ---- BN2 + ELU applied in place on f32 d_out ----
__global__ __launch_bounds__(256) void bn_elu_out(float* __restrict__ out,
                                                  const float* __restrict__ ab) {
    int tid = blockIdx.x * 256 + threadIdx.x;
    int c0 = (tid * 4) & 63;
    float av[4], bv[4];
#pragma unroll
    for (int j = 0; j < 4; ++j) { av[j] = ab[c0 + j]; bv[j] = ab[64 + c0 + j]; }
#pragma unroll
    for (int t = 0; t < 8; ++t) {
        size_t e = ((size_t)t * 1048576 + tid) * 4;
        f32x4 v = *(const f32x4*)(out + e);
        f32x4 o;
#pragma unroll
        for (int j = 0; j < 4; ++j) o[j] = elu_f(v[j] * av[j] + bv[j]);
        *(f32x4*)(out + e) = o;
    }
}

extern "C" void kernel_launch(void* const* d_in, const int* in_sizes, int n_in,
                              void* d_out, int out_size, void* d_ws, size_t ws_size,
                              hipStream_t stream) {
    const float* x     = (const float*)d_in[0];
    const int*   neigh = (const int*)d_in[1];
    const float* wup   = (const float*)d_in[2];
    const float* wcv   = (const float*)d_in[3];
    const float* g1    = (const float*)d_in[4];
    const float* b1    = (const float*)d_in[5];
    const float* g2    = (const float*)d_in[6];
    const float* b2    = (const float*)d_in[7];
    float* out = (float*)d_out;

    char* ws = (char*)d_ws;
    __bf16* y     = (__bf16*)(ws + Y_OFF);
    __bf16* wtup  = (__bf16*)(ws + WTUP_OFF);
    __bf16* wtcv  = (__bf16*)(ws + WTCV_OFF);
    float*  bins1 = (float*)(ws + S1_OFF);
    float*  bins2 = (float*)(ws + S2_OFF);
    float*  ab1   = (float*)(ws + AB1_OFF);
    float*  ab2   = (float*)(ws + AB2_OFF);

    hipMemsetAsync(ws + S1_OFF, 0, 32768u * 2 + 1024u, stream);

    prep_w<<<688, 256, 0, stream>>>(wup, wcv, wtup, wtcv);
    deconv_bn_stats<<<N_PARENT / 16, 256, 0, stream>>>(x, wtup, y, bins1);
    finalize_stats<<<1, 64, 0, stream>>>(bins1, g1, b1, ab1, 1.f / (float)N_CHILD);
    bn_elu_y<<<4096, 256, 0, stream>>>(y, ab1);
    conv_bn_stats<<<N_CHILD / 256, 256, 0, stream>>>(y, neigh, wtcv, out, bins2);
    finalize_stats<<<1, 64, 0, stream>>>(bins2, g2, b2, ab2, 1.f / (float)N_CHILD);
    bn_elu_out<<<4096, 256, 0, stream>>>(out, ab2);
}

// Round 3
// 634.602 us; speedup vs baseline: 1.0242x; 1.0242x over previous
//
#include <hip/hip_runtime.h>

// UpBlock: deconv(8-oct GEMM) -> BN+ELU -> 27-tap gather conv -> BN+ELU
// R3: conv gathers full 128-B rows via global_load_lds into per-wave private
// LDS tiles (halves L2 request count vs 2x64-B half-row loads), XOR-swizzled
// both sides; per-lane tap indices in VGPRs redistributed with ds_bpermute.

#define N_PARENT 65536
#define C_IN     128
#define C_OUT    64
#define N_CHILD  (N_PARENT * 8)
#define TAPS     27
#define NBINS    64

typedef __bf16 bf16x8 __attribute__((ext_vector_type(8)));
typedef float  f32x4  __attribute__((ext_vector_type(4)));

// workspace layout (bytes)
#define Y_OFF     0u               // bf16 y [N_CHILD][64]  = 67108864
#define WTUP_OFF  67108864u        // bf16 WtUp [8][64 n][128 k] = 131072
#define WTCV_OFF  67239936u        // bf16 WtCv [27][64 n][64 k] = 221184
#define S1_OFF    67461120u        // f32 bins1 [64][128]   = 32768
#define S2_OFF    67493888u        // f32 bins2 [64][128]   = 32768
#define AB1_OFF   67526656u        // f32 a1[64], b1[64]    = 512
#define AB2_OFF   67527168u        // f32 a2[64], b2[64]    = 512

__device__ __forceinline__ float elu_f(float f) {
    return f > 0.f ? f : (__expf(f) - 1.f);
}

__device__ __forceinline__ void gload_lds16(const void* g, void* l) {
    __builtin_amdgcn_global_load_lds((const __attribute__((address_space(1))) void*)g,
                                     (__attribute__((address_space(3))) void*)l, 16, 0, 0);
}

// ---- prep: transpose weights to [n][k] layout, cast to bf16 ----
__global__ __launch_bounds__(256) void prep_w(const float* __restrict__ wup,
                                              const float* __restrict__ wcv,
                                              __bf16* __restrict__ wtup,
                                              __bf16* __restrict__ wtcv) {
    int i = blockIdx.x * 256 + threadIdx.x;
    if (i < 8 * 64 * 128) {
        int o = i >> 13, rem = i & 8191, n = rem >> 7, k = rem & 127;
        wtup[i] = (__bf16)wup[o * 8192 + k * 64 + n];
    } else {
        int j = i - 65536;                     // j < 27*64*64 = 110592
        int t = j >> 12, rem = j & 4095, n = rem >> 6, k = rem & 63;
        wtcv[j] = (__bf16)wcv[t * 4096 + k * 64 + n];
    }
}

// ---- kernel A: y[8p+oct] = x[p] @ W_up[oct], accumulate BN1 stats ----
__global__ __launch_bounds__(256) void deconv_bn_stats(
    const float* __restrict__ x, const __bf16* __restrict__ wtup,
    __bf16* __restrict__ y, float* __restrict__ bins) {
    __shared__ float ssum[64], ssq[64];
    int tid = threadIdx.x;
    int wave = tid >> 6, lane = tid & 63, lr = lane & 15, lg = lane >> 4;
    int p0 = blockIdx.x * 16;

    if (tid < 64) { ssum[tid] = 0.f; ssq[tid] = 0.f; }

    const float* xrow = x + (size_t)(p0 + lr) * C_IN;
    bf16x8 afr[4];
#pragma unroll
    for (int ks = 0; ks < 4; ++ks) {
        const float* src = xrow + ks * 32 + lg * 8;
        f32x4 u0 = *(const f32x4*)(src);
        f32x4 u1 = *(const f32x4*)(src + 4);
        bf16x8 a;
#pragma unroll
        for (int i = 0; i < 4; ++i) { a[i] = (__bf16)u0[i]; a[4 + i] = (__bf16)u1[i]; }
        afr[ks] = a;
    }

    float lsum[4] = {0.f, 0.f, 0.f, 0.f}, lsq[4] = {0.f, 0.f, 0.f, 0.f};
#pragma unroll
    for (int oo = 0; oo < 2; ++oo) {
        int oct = wave * 2 + oo;
#pragma unroll
        for (int nt = 0; nt < 4; ++nt) {
            f32x4 acc = {0.f, 0.f, 0.f, 0.f};
#pragma unroll
            for (int ks = 0; ks < 4; ++ks) {
                const __bf16* bp = wtup + ((size_t)(oct * 64 + nt * 16 + lr) * C_IN + ks * 32 + lg * 8);
                bf16x8 b = *(const bf16x8*)bp;
                acc = __builtin_amdgcn_mfma_f32_16x16x32_bf16(afr[ks], b, acc, 0, 0, 0);
            }
#pragma unroll
            for (int r = 0; r < 4; ++r) {
                int parent = p0 + lg * 4 + r;
                int child = parent * 8 + oct;
                float v = acc[r];
                y[(size_t)child * C_OUT + nt * 16 + lr] = (__bf16)v;
                lsum[nt] += v; lsq[nt] += v * v;
            }
        }
    }
    __syncthreads();
#pragma unroll
    for (int nt = 0; nt < 4; ++nt) {
        atomicAdd(&ssum[nt * 16 + lr], lsum[nt]);
        atomicAdd(&ssq[nt * 16 + lr], lsq[nt]);
    }
    __syncthreads();
    if (tid < 64) {
        float* b = bins + (size_t)(blockIdx.x & (NBINS - 1)) * 128;
        atomicAdd(&b[tid], ssum[tid]);
        atomicAdd(&b[64 + tid], ssq[tid]);
    }
}

// ---- finalize: per-channel a = gamma*rstd, b = beta - mu*a ----
__global__ void finalize_stats(const float* __restrict__ bins,
                               const float* __restrict__ gamma,
                               const float* __restrict__ beta,
                               float* __restrict__ ab, float invN) {
    int c = threadIdx.x;  // 64 threads
    float s = 0.f, q = 0.f;
    for (int b = 0; b < NBINS; ++b) { s += bins[b * 128 + c]; q += bins[b * 128 + 64 + c]; }
    float mu = s * invN;
    float var = q * invN - mu * mu;
    float rstd = rsqrtf(var + 1e-5f);
    float a = gamma[c] * rstd;
    ab[c] = a;
    ab[64 + c] = beta[c] - mu * a;
}

// ---- BN1 + ELU applied in place on bf16 y ----
__global__ __launch_bounds__(256) void bn_elu_y(__bf16* __restrict__ y,
                                                const float* __restrict__ ab) {
    int tid = blockIdx.x * 256 + threadIdx.x;
    int c0 = (tid * 8) & 63;
    float av[8], bv[8];
#pragma unroll
    for (int j = 0; j < 8; ++j) { av[j] = ab[c0 + j]; bv[j] = ab[64 + c0 + j]; }
#pragma unroll
    for (int t = 0; t < 4; ++t) {
        size_t e = ((size_t)t * 1048576 + tid) * 8;
        bf16x8 v = *(const bf16x8*)(y + e);
        bf16x8 o;
#pragma unroll
        for (int j = 0; j < 8; ++j) {
            float f = (float)v[j] * av[j] + bv[j];
            o[j] = (__bf16)elu_f(f);
        }
        *(bf16x8*)(y + e) = o;
    }
}

// ---- kernel C: 27-tap gather conv, full-row LDS gathers ----
// 256 thr = 4 waves; each wave owns 32 rows x 64 cols, private 4 KB LDS tile.
// Per tap: 4 global_load_lds (8 full 128-B rows each), XOR-swizzled source;
// fragments via swizzled ds_read_b128. Indices: 27 VGPRs/lane + ds_bpermute.
__global__ __launch_bounds__(256) void conv_bn_stats(
    const __bf16* __restrict__ y, const int* __restrict__ neigh,
    const __bf16* __restrict__ wtcv, float* __restrict__ out,
    float* __restrict__ bins) {
    __shared__ __align__(16) char gmem[4][4096];
    __shared__ float ssum[64], ssq[64];
    int tid = threadIdx.x;
    int wave = tid >> 6, lane = tid & 63, lr = lane & 15, lg = lane >> 4;
    int r0 = blockIdx.x * 128 + wave * 32;      // wave's first output row

    if (tid < 64) { ssum[tid] = 0.f; ssq[tid] = 0.f; }

    char* gbuf = gmem[wave];
    const char* ybytes = (const char*)y;
    int swz = (((lane & 7) ^ (lane >> 3)) << 4);      // source chunk XOR-swizzle (bytes)
    int bperm_base = (lane >> 3) << 2;                // byte index of source lane group

    // ---- stage this wave's 32x27 neighbor indices into VGPRs via LDS bounce ----
    int idx_r[TAPS];
    {
        int base_w = r0 * TAPS;                       // first neigh word
#pragma unroll
        for (int j = 0; j < 14; ++j) {
            int w = j * 64 + lane;
            if (w < 32 * TAPS) {
                int v = neigh[base_w + w];
                *(int*)(gbuf + w * 4) = v;
            }
        }
        asm volatile("s_waitcnt lgkmcnt(0)" ::: "memory");
        __builtin_amdgcn_sched_barrier(0);
#pragma unroll
        for (int k = 0; k < TAPS; ++k)
            idx_r[k] = *(const int*)(gbuf + ((lane & 31) * TAPS + k) * 4);
        asm volatile("s_waitcnt lgkmcnt(0)" ::: "memory");
        __builtin_amdgcn_sched_barrier(0);
    }

    f32x4 acc[2][4];
#pragma unroll
    for (int mt = 0; mt < 2; ++mt)
#pragma unroll
        for (int nt = 0; nt < 4; ++nt) acc[mt][nt] = (f32x4){0.f, 0.f, 0.f, 0.f};

    // ---- prologue: gather tap 0 ----
    {
        int v = idx_r[0];
#pragma unroll
        for (int i = 0; i < 4; ++i) {
            int g = __builtin_amdgcn_ds_bpermute((i << 5) + bperm_base, v);
            gload_lds16(ybytes + (size_t)(unsigned)g * 128 + swz, gbuf + i * 1024);
        }
    }

#pragma unroll
    for (int k = 0; k < TAPS; ++k) {
        // bpermute next tap's gather row indices (overlaps with gather latency)
        int gn[4];
        if (k < TAPS - 1) {
            int v = idx_r[k + 1];
#pragma unroll
            for (int i = 0; i < 4; ++i)
                gn[i] = __builtin_amdgcn_ds_bpermute((i << 5) + bperm_base, v);
        }
        // B fragments for tap k (wtcv is L1/L2-resident)
        const __bf16* wk = wtcv + (size_t)k * 4096 + lr * 64 + lg * 8;
        bf16x8 bfr[4][2];
#pragma unroll
        for (int nt = 0; nt < 4; ++nt) {
            bfr[nt][0] = *(const bf16x8*)(wk + nt * 1024);
            bfr[nt][1] = *(const bf16x8*)(wk + nt * 1024 + 32);
        }
        // wait for tap-k gathered rows to land in LDS (drains B too: L1-cheap)
        asm volatile("s_waitcnt vmcnt(0)" ::: "memory");
        __builtin_amdgcn_sched_barrier(0);
        // A fragments: row s = mt*16+lr, chunk (ks*4+lg)^(lr&7)
        bf16x8 afr[2][2];
#pragma unroll
        for (int mt = 0; mt < 2; ++mt)
#pragma unroll
            for (int ks = 0; ks < 2; ++ks) {
                int s = mt * 16 + lr;
                int chunk = (ks * 4 + lg) ^ (lr & 7);
                afr[mt][ks] = *(const bf16x8*)(gbuf + s * 128 + chunk * 16);
            }
        asm volatile("s_waitcnt lgkmcnt(0)" ::: "memory");
        __builtin_amdgcn_sched_barrier(0);
        // issue tap k+1 gathers (WAR-safe: all tap-k fragment reads completed)
        if (k < TAPS - 1) {
#pragma unroll
            for (int i = 0; i < 4; ++i)
                gload_lds16(ybytes + (size_t)(unsigned)gn[i] * 128 + swz, gbuf + i * 1024);
        }
        // MFMAs
#pragma unroll
        for (int ks = 0; ks < 2; ++ks)
#pragma unroll
            for (int mt = 0; mt < 2; ++mt)
#pragma unroll
                for (int nt = 0; nt < 4; ++nt)
                    acc[mt][nt] = __builtin_amdgcn_mfma_f32_16x16x32_bf16(
                        afr[mt][ks], bfr[nt][ks], acc[mt][nt], 0, 0, 0);
    }

    float lsum[4] = {0.f, 0.f, 0.f, 0.f}, lsq[4] = {0.f, 0.f, 0.f, 0.f};
#pragma unroll
    for (int mt = 0; mt < 2; ++mt)
#pragma unroll
        for (int nt = 0; nt < 4; ++nt)
#pragma unroll
            for (int r = 0; r < 4; ++r) {
                float v = acc[mt][nt][r];
                int row = r0 + mt * 16 + lg * 4 + r;
                out[(size_t)row * C_OUT + nt * 16 + lr] = v;
                lsum[nt] += v; lsq[nt] += v * v;
            }
    __syncthreads();
#pragma unroll
    for (int nt = 0; nt < 4; ++nt) {
        atomicAdd(&ssum[nt * 16 + lr], lsum[nt]);
        atomicAdd(&ssq[nt * 16 + lr], lsq[nt]);
    }
    __syncthreads();
    if (tid < 64) {
        float* b = bins + (size_t)(blockIdx.x & (NBINS - 1)) * 128;
        atomicAdd(&b[tid], ssum[tid]);
        atomicAdd(&b[64 + tid], ssq[tid]);
    }
}

// ---- BN2 + ELU applied in place on f32 d_out ----
__global__ __launch_bounds__(256) void bn_elu_out(float* __restrict__ out,
                                                  const float* __restrict__ ab) {
    int tid = blockIdx.x * 256 + threadIdx.x;
    int c0 = (tid * 4) & 63;
    float av[4], bv[4];
#pragma unroll
    for (int j = 0; j < 4; ++j) { av[j] = ab[c0 + j]; bv[j] = ab[64 + c0 + j]; }
#pragma unroll
    for (int t = 0; t < 8; ++t) {
        size_t e = ((size_t)t * 1048576 + tid) * 4;
        f32x4 v = *(const f32x4*)(out + e);
        f32x4 o;
#pragma unroll
        for (int j = 0; j < 4; ++j) o[j] = elu_f(v[j] * av[j] + bv[j]);
        *(f32x4*)(out + e) = o;
    }
}

extern "C" void kernel_launch(void* const* d_in, const int* in_sizes, int n_in,
                              void* d_out, int out_size, void* d_ws, size_t ws_size,
                              hipStream_t stream) {
    const float* x     = (const float*)d_in[0];
    const int*   neigh = (const int*)d_in[1];
    const float* wup   = (const float*)d_in[2];
    const float* wcv   = (const float*)d_in[3];
    const float* g1    = (const float*)d_in[4];
    const float* b1    = (const float*)d_in[5];
    const float* g2    = (const float*)d_in[6];
    const float* b2    = (const float*)d_in[7];
    float* out = (float*)d_out;

    char* ws = (char*)d_ws;
    __bf16* y     = (__bf16*)(ws + Y_OFF);
    __bf16* wtup  = (__bf16*)(ws + WTUP_OFF);
    __bf16* wtcv  = (__bf16*)(ws + WTCV_OFF);
    float*  bins1 = (float*)(ws + S1_OFF);
    float*  bins2 = (float*)(ws + S2_OFF);
    float*  ab1   = (float*)(ws + AB1_OFF);
    float*  ab2   = (float*)(ws + AB2_OFF);

    hipMemsetAsync(ws + S1_OFF, 0, 32768u * 2 + 1024u, stream);

    prep_w<<<688, 256, 0, stream>>>(wup, wcv, wtup, wtcv);
    deconv_bn_stats<<<N_PARENT / 16, 256, 0, stream>>>(x, wtup, y, bins1);
    finalize_stats<<<1, 64, 0, stream>>>(bins1, g1, b1, ab1, 1.f / (float)N_CHILD);
    bn_elu_y<<<4096, 256, 0, stream>>>(y, ab1);
    conv_bn_stats<<<N_CHILD / 128, 256, 0, stream>>>(y, neigh, wtcv, out, bins2);
    finalize_stats<<<1, 64, 0, stream>>>(bins2, g2, b2, ab2, 1.f / (float)N_CHILD);
    bn_elu_out<<<4096, 256, 0, stream>>>(out, ab2);
}

// Round 4
// 597.379 us; speedup vs baseline: 1.0880x; 1.0623x over previous
//
#include <hip/hip_runtime.h>

// UpBlock: deconv(8-oct GEMM) -> BN+ELU -> 27-tap gather conv -> BN+ELU
// R4: conv gathers int8 rows (64 B, per-row scale) instead of bf16 (128 B):
// halves both L3-path demand bytes and lane-address count. i8 MFMA K=64,
// per-tap f32 scale-accumulate; W int8 per-column scales cancel in BN2.

#define N_PARENT 65536
#define C_IN     128
#define C_OUT    64
#define N_CHILD  (N_PARENT * 8)
#define TAPS     27
#define NBINS    64

typedef __bf16 bf16x8 __attribute__((ext_vector_type(8)));
typedef float  f32x4  __attribute__((ext_vector_type(4)));
typedef int    i32x4  __attribute__((ext_vector_type(4)));
typedef int    i32x2  __attribute__((ext_vector_type(2)));

// workspace layout (bytes)
#define Y_OFF     0u          // rows [N_CHILD][128B]: bf16 h, then int8 y8 in first 64B
#define S_OFF     67108864u   // f32 s[N_CHILD] per-row scales = 2097152
#define WTUP_OFF  69206016u   // bf16 WtUp [8][64 n][128 k] = 131072
#define W8CV_OFF  69337088u   // i8 Wt8 [27][64 n][64 j] = 110592
#define TINV_OFF  69447680u   // f32 Tinv[64] = 256
#define S1_OFF    69447936u   // f32 bins1 [64][128] = 32768
#define S2_OFF    69480704u   // f32 bins2 [64][128] = 32768
#define AB1_OFF   69513472u   // f32 a1[64], b1[64] = 512
#define AB2_OFF   69513984u   // f32 a2[64], b2[64] = 512

__device__ __forceinline__ float elu_f(float f) {
    return f > 0.f ? f : (__expf(f) - 1.f);
}

__device__ __forceinline__ void gload_lds16(const void* g, void* l) {
    __builtin_amdgcn_global_load_lds((const __attribute__((address_space(1))) void*)g,
                                     (__attribute__((address_space(3))) void*)l, 16, 0, 0);
}

// ---- prep_tc: per-output-column absmax of W_conv -> Tinv[c] = 127/max ----
__global__ __launch_bounds__(256) void prep_tc(const float* __restrict__ wcv,
                                               float* __restrict__ tinv) {
    __shared__ float part[4][64];
    int t = threadIdx.x, c = t & 63, q = t >> 6;
    float m = 0.f;
    for (int i = q; i < 1728; i += 4) m = fmaxf(m, fabsf(wcv[i * 64 + c]));
    part[q][c] = m;
    __syncthreads();
    if (t < 64) {
        float mm = fmaxf(fmaxf(part[0][t], part[1][t]), fmaxf(part[2][t], part[3][t]));
        tinv[t] = 127.f / fmaxf(mm, 1e-20f);
    }
}

// ---- prep: WtUp transpose->bf16; W_conv -> int8 [27][n][j] with Tinv[n] ----
__global__ __launch_bounds__(256) void prep_w(const float* __restrict__ wup,
                                              const float* __restrict__ wcv,
                                              __bf16* __restrict__ wtup,
                                              signed char* __restrict__ w8,
                                              const float* __restrict__ tinv) {
    int i = blockIdx.x * 256 + threadIdx.x;
    if (i < 8 * 64 * 128) {
        int o = i >> 13, rem = i & 8191, n = rem >> 7, k = rem & 127;
        wtup[i] = (__bf16)wup[o * 8192 + k * 64 + n];
    } else {
        int j2 = i - 65536;                   // j2 < 27*64*64 = 110592
        int t = j2 >> 12, rem = j2 & 4095, n = rem >> 6, j = rem & 63;
        float v = wcv[(t * 64 + j) * 64 + n] * tinv[n];
        w8[j2] = (signed char)(int)rintf(v);
    }
}

// ---- kernel A: h[8p+oct] = x[p] @ W_up[oct] (bf16), accumulate BN1 stats ----
// rows stored at stride 128 B (64 bf16).
__global__ __launch_bounds__(256) void deconv_bn_stats(
    const float* __restrict__ x, const __bf16* __restrict__ wtup,
    __bf16* __restrict__ y, float* __restrict__ bins) {
    __shared__ float ssum[64], ssq[64];
    int tid = threadIdx.x;
    int wave = tid >> 6, lane = tid & 63, lr = lane & 15, lg = lane >> 4;
    int p0 = blockIdx.x * 16;

    if (tid < 64) { ssum[tid] = 0.f; ssq[tid] = 0.f; }

    const float* xrow = x + (size_t)(p0 + lr) * C_IN;
    bf16x8 afr[4];
#pragma unroll
    for (int ks = 0; ks < 4; ++ks) {
        const float* src = xrow + ks * 32 + lg * 8;
        f32x4 u0 = *(const f32x4*)(src);
        f32x4 u1 = *(const f32x4*)(src + 4);
        bf16x8 a;
#pragma unroll
        for (int i = 0; i < 4; ++i) { a[i] = (__bf16)u0[i]; a[4 + i] = (__bf16)u1[i]; }
        afr[ks] = a;
    }

    float lsum[4] = {0.f, 0.f, 0.f, 0.f}, lsq[4] = {0.f, 0.f, 0.f, 0.f};
#pragma unroll
    for (int oo = 0; oo < 2; ++oo) {
        int oct = wave * 2 + oo;
#pragma unroll
        for (int nt = 0; nt < 4; ++nt) {
            f32x4 acc = {0.f, 0.f, 0.f, 0.f};
#pragma unroll
            for (int ks = 0; ks < 4; ++ks) {
                const __bf16* bp = wtup + ((size_t)(oct * 64 + nt * 16 + lr) * C_IN + ks * 32 + lg * 8);
                bf16x8 b = *(const bf16x8*)bp;
                acc = __builtin_amdgcn_mfma_f32_16x16x32_bf16(afr[ks], b, acc, 0, 0, 0);
            }
#pragma unroll
            for (int r = 0; r < 4; ++r) {
                int parent = p0 + lg * 4 + r;
                int child = parent * 8 + oct;
                float v = acc[r];
                y[(size_t)child * 64 + nt * 16 + lr] = (__bf16)v;
                lsum[nt] += v; lsq[nt] += v * v;
            }
        }
    }
    __syncthreads();
#pragma unroll
    for (int nt = 0; nt < 4; ++nt) {
        atomicAdd(&ssum[nt * 16 + lr], lsum[nt]);
        atomicAdd(&ssq[nt * 16 + lr], lsq[nt]);
    }
    __syncthreads();
    if (tid < 64) {
        float* b = bins + (size_t)(blockIdx.x & (NBINS - 1)) * 128;
        atomicAdd(&b[tid], ssum[tid]);
        atomicAdd(&b[64 + tid], ssq[tid]);
    }
}

// ---- finalize: per-channel a = gamma*rstd, b = beta - mu*a ----
__global__ void finalize_stats(const float* __restrict__ bins,
                               const float* __restrict__ gamma,
                               const float* __restrict__ beta,
                               float* __restrict__ ab, float invN) {
    int c = threadIdx.x;  // 64 threads
    float s = 0.f, q = 0.f;
    for (int b = 0; b < NBINS; ++b) { s += bins[b * 128 + c]; q += bins[b * 128 + 64 + c]; }
    float mu = s * invN;
    float var = q * invN - mu * mu;
    float rstd = rsqrtf(var + 1e-5f);
    float a = gamma[c] * rstd;
    ab[c] = a;
    ab[64 + c] = beta[c] - mu * a;
}

// ---- BN1 + ELU + per-row int8 quant, in place (8 threads per row) ----
__global__ __launch_bounds__(256) void bn_elu_quant(char* __restrict__ ybuf,
                                                    float* __restrict__ sArr,
                                                    const float* __restrict__ ab) {
    int gt = blockIdx.x * 256 + threadIdx.x;
    int row = gt >> 3, tc = gt & 7;
    int c0 = tc * 8;
    const __bf16* yr = (const __bf16*)(ybuf + (size_t)row * 128);
    bf16x8 h = *(const bf16x8*)(yr + c0);
    float v[8];
    float m = 0.f;
#pragma unroll
    for (int j = 0; j < 8; ++j) {
        float f = (float)h[j] * ab[c0 + j] + ab[64 + c0 + j];
        f = elu_f(f);
        v[j] = f;
        m = fmaxf(m, fabsf(f));
    }
    // row max across the 8 threads of this row (contiguous lanes)
    m = fmaxf(m, __shfl_xor(m, 1));
    m = fmaxf(m, __shfl_xor(m, 2));
    m = fmaxf(m, __shfl_xor(m, 4));
    m = fmaxf(m, 1e-6f);
    float inv = 127.f / m;
    int lo = 0, hi = 0;
#pragma unroll
    for (int j = 0; j < 4; ++j) {
        int q0 = (int)rintf(v[j] * inv);
        int q1 = (int)rintf(v[4 + j] * inv);
        lo |= (q0 & 255) << (8 * j);
        hi |= (q1 & 255) << (8 * j);
    }
    i32x2 pk; pk[0] = lo; pk[1] = hi;
    *(i32x2*)(ybuf + (size_t)row * 128 + tc * 8) = pk;
    if (tc == 0) sArr[row] = m * (1.f / 127.f);
}

// ---- kernel C: 27-tap gather conv, int8 rows + per-row scales ----
// 256 thr = 4 waves; each wave: 32 rows x 64 cols. Per tap: 2 gload_lds
// (16 rows x 64 B each, XOR-swizzled both sides), 8x mfma_i32_16x16x64_i8,
// f32 scale-accumulate with s from per-wave LDS table.
__global__ __launch_bounds__(256) void conv_bn_stats(
    const char* __restrict__ ybuf, const int* __restrict__ neigh,
    const signed char* __restrict__ w8, const float* __restrict__ sArr,
    float* __restrict__ out, float* __restrict__ bins) {
    __shared__ __align__(16) char lds[4][5504];   // [0,2048) tile, [2048,5504) s/idx
    __shared__ float ssum[64], ssq[64];
    int tid = threadIdx.x;
    int wave = tid >> 6, lane = tid & 63, lr = lane & 15, lg = lane >> 4;
    int r0 = blockIdx.x * 128 + wave * 32;

    if (tid < 64) { ssum[tid] = 0.f; ssq[tid] = 0.f; }

    char* tile = lds[wave];
    char* sreg = lds[wave] + 2048;

    // per-lane constants
    // gather source swizzle: LDS slot s of tile-row r holds global chunk (s-(r>>1))&3
    int srcoff = (((lane & 3) + 4 - ((lane >> 2) >> 1)) & 3) * 16;
    int aoff0 = (lr + 0) * 64 + (((lg) + (lr >> 1)) & 3) * 16;   // A read, mt=0
    int aoff1 = (lr + 16) * 64 + (((lg) + (lr >> 1)) & 3) * 16;  // A read, mt=1
    int soff0 = (lg * 4 + 0) * 4;                                 // s_tile read, mt=0
    int soff1 = (lg * 4 + 16) * 4;

    // ---- stage 32x27 neighbor indices into VGPRs via LDS bounce ----
    int idx_r[TAPS];
    {
        int base_w = r0 * TAPS;
#pragma unroll
        for (int j = 0; j < 14; ++j) {
            int w = j * 64 + lane;
            if (w < 32 * TAPS) {
                int v = neigh[base_w + w];
                *(int*)(sreg + w * 4) = v;
            }
        }
        asm volatile("s_waitcnt lgkmcnt(0)" ::: "memory");
        __builtin_amdgcn_sched_barrier(0);
#pragma unroll
        for (int k = 0; k < TAPS; ++k)
            idx_r[k] = *(const int*)(sreg + ((lane & 31) * TAPS + k) * 4);
        asm volatile("s_waitcnt lgkmcnt(0)" ::: "memory");
        __builtin_amdgcn_sched_barrier(0);
    }
    // ---- stage per-row scales for all taps: s_tile[k][32] over same region ----
    if (lane < 32) {
#pragma unroll
        for (int k = 0; k < TAPS; ++k) {
            float sv = sArr[idx_r[k]];
            *(float*)(sreg + (k * 32 + lane) * 4) = sv;
        }
    }
    asm volatile("s_waitcnt vmcnt(0) lgkmcnt(0)" ::: "memory");
    __builtin_amdgcn_sched_barrier(0);

    f32x4 facc[2][4];
#pragma unroll
    for (int mt = 0; mt < 2; ++mt)
#pragma unroll
        for (int nt = 0; nt < 4; ++nt) facc[mt][nt] = (f32x4){0.f, 0.f, 0.f, 0.f};

    const signed char* w8l = w8 + lr * 64 + lg * 16;

    // ---- prologue: gather tap 0 (2 instrs x 16 rows x 64 B) ----
    {
#pragma unroll
        for (int i = 0; i < 2; ++i) {
            int g = __builtin_amdgcn_ds_bpermute(((i << 4) + (lane >> 2)) << 2, idx_r[0]);
            gload_lds16(ybuf + (size_t)(unsigned)g * 128 + srcoff, tile + i * 1024);
        }
    }

#pragma unroll
    for (int k = 0; k < TAPS; ++k) {
        // next-tap gather row indices
        int gn[2];
        if (k < TAPS - 1) {
#pragma unroll
            for (int i = 0; i < 2; ++i)
                gn[i] = __builtin_amdgcn_ds_bpermute(((i << 4) + (lane >> 2)) << 2, idx_r[k + 1]);
        }
        // B fragments for tap k (int8, L2-resident)
        const signed char* wk = w8l + k * 4096;
        i32x4 bfr[4];
#pragma unroll
        for (int nt = 0; nt < 4; ++nt) bfr[nt] = *(const i32x4*)(wk + nt * 1024);
        // wait for tap-k rows in LDS (drains B loads too)
        asm volatile("s_waitcnt vmcnt(0)" ::: "memory");
        __builtin_amdgcn_sched_barrier(0);
        // A fragments + scales from LDS
        i32x4 afr0 = *(const i32x4*)(tile + aoff0);
        i32x4 afr1 = *(const i32x4*)(tile + aoff1);
        f32x4 sv0 = *(const f32x4*)(sreg + k * 128 + soff0);
        f32x4 sv1 = *(const f32x4*)(sreg + k * 128 + soff1);
        asm volatile("s_waitcnt lgkmcnt(0)" ::: "memory");
        __builtin_amdgcn_sched_barrier(0);
        // issue tap k+1 gathers (WAR-safe: tile reads done)
        if (k < TAPS - 1) {
#pragma unroll
            for (int i = 0; i < 2; ++i)
                gload_lds16(ybuf + (size_t)(unsigned)gn[i] * 128 + srcoff, tile + i * 1024);
        }
        // MFMAs + dequant-accumulate
#pragma unroll
        for (int nt = 0; nt < 4; ++nt) {
            i32x4 r0 = __builtin_amdgcn_mfma_i32_16x16x64_i8(afr0, bfr[nt], (i32x4){0,0,0,0}, 0, 0, 0);
            i32x4 r1 = __builtin_amdgcn_mfma_i32_16x16x64_i8(afr1, bfr[nt], (i32x4){0,0,0,0}, 0, 0, 0);
#pragma unroll
            for (int j = 0; j < 4; ++j) {
                facc[0][nt][j] += sv0[j] * (float)r0[j];
                facc[1][nt][j] += sv1[j] * (float)r1[j];
            }
        }
    }

    float lsum[4] = {0.f, 0.f, 0.f, 0.f}, lsq[4] = {0.f, 0.f, 0.f, 0.f};
#pragma unroll
    for (int mt = 0; mt < 2; ++mt)
#pragma unroll
        for (int nt = 0; nt < 4; ++nt)
#pragma unroll
            for (int r = 0; r < 4; ++r) {
                float v = facc[mt][nt][r];
                int row = r0 + mt * 16 + lg * 4 + r;
                out[(size_t)row * C_OUT + nt * 16 + lr] = v;
                lsum[nt] += v; lsq[nt] += v * v;
            }
    __syncthreads();
#pragma unroll
    for (int nt = 0; nt < 4; ++nt) {
        atomicAdd(&ssum[nt * 16 + lr], lsum[nt]);
        atomicAdd(&ssq[nt * 16 + lr], lsq[nt]);
    }
    __syncthreads();
    if (tid < 64) {
        float* b = bins + (size_t)(blockIdx.x & (NBINS - 1)) * 128;
        atomicAdd(&b[tid], ssum[tid]);
        atomicAdd(&b[64 + tid], ssq[tid]);
    }
}

// ---- BN2 + ELU applied in place on f32 d_out ----
__global__ __launch_bounds__(256) void bn_elu_out(float* __restrict__ out,
                                                  const float* __restrict__ ab) {
    int tid = blockIdx.x * 256 + threadIdx.x;
    int c0 = (tid * 4) & 63;
    float av[4], bv[4];
#pragma unroll
    for (int j = 0; j < 4; ++j) { av[j] = ab[c0 + j]; bv[j] = ab[64 + c0 + j]; }
#pragma unroll
    for (int t = 0; t < 8; ++t) {
        size_t e = ((size_t)t * 1048576 + tid) * 4;
        f32x4 v = *(const f32x4*)(out + e);
        f32x4 o;
#pragma unroll
        for (int j = 0; j < 4; ++j) o[j] = elu_f(v[j] * av[j] + bv[j]);
        *(f32x4*)(out + e) = o;
    }
}

extern "C" void kernel_launch(void* const* d_in, const int* in_sizes, int n_in,
                              void* d_out, int out_size, void* d_ws, size_t ws_size,
                              hipStream_t stream) {
    const float* x     = (const float*)d_in[0];
    const int*   neigh = (const int*)d_in[1];
    const float* wup   = (const float*)d_in[2];
    const float* wcv   = (const float*)d_in[3];
    const float* g1    = (const float*)d_in[4];
    const float* b1    = (const float*)d_in[5];
    const float* g2    = (const float*)d_in[6];
    const float* b2    = (const float*)d_in[7];
    float* out = (float*)d_out;

    char* ws = (char*)d_ws;
    char*        ybuf  = ws + Y_OFF;
    float*       sArr  = (float*)(ws + S_OFF);
    __bf16*      wtup  = (__bf16*)(ws + WTUP_OFF);
    signed char* w8    = (signed char*)(ws + W8CV_OFF);
    float*       tinv  = (float*)(ws + TINV_OFF);
    float*       bins1 = (float*)(ws + S1_OFF);
    float*       bins2 = (float*)(ws + S2_OFF);
    float*       ab1   = (float*)(ws + AB1_OFF);
    float*       ab2   = (float*)(ws + AB2_OFF);

    hipMemsetAsync(ws + S1_OFF, 0, 32768u * 2 + 1024u, stream);

    prep_tc<<<1, 256, 0, stream>>>(wcv, tinv);
    prep_w<<<688, 256, 0, stream>>>(wup, wcv, wtup, w8, tinv);
    deconv_bn_stats<<<N_PARENT / 16, 256, 0, stream>>>(x, wtup, (__bf16*)ybuf, bins1);
    finalize_stats<<<1, 64, 0, stream>>>(bins1, g1, b1, ab1, 1.f / (float)N_CHILD);
    bn_elu_quant<<<16384, 256, 0, stream>>>(ybuf, sArr, ab1);
    conv_bn_stats<<<N_CHILD / 128, 256, 0, stream>>>(ybuf, neigh, w8, sArr, out, bins2);
    finalize_stats<<<1, 64, 0, stream>>>(bins2, g2, b2, ab2, 1.f / (float)N_CHILD);
    bn_elu_out<<<4096, 256, 0, stream>>>(out, ab2);
}

// Round 5
// 505.889 us; speedup vs baseline: 1.2848x; 1.1808x over previous
//
#include <hip/hip_runtime.h>

// UpBlock: deconv(8-oct GEMM) -> BN+ELU -> 27-tap gather conv -> BN+ELU
// R5: conv pipeline 2 taps deep with counted vmcnt(6) (never 0 in steady
// state), double-buffered LDS gather tiles + double-buffered B registers;
// scales staged bf16 in LDS; indices ds_read per tap. prep_tc -> 64 blocks.

#define N_PARENT 65536
#define C_IN     128
#define C_OUT    64
#define N_CHILD  (N_PARENT * 8)
#define TAPS     27
#define NBINS    64

typedef __bf16 bf16x8 __attribute__((ext_vector_type(8)));
typedef float  f32x4  __attribute__((ext_vector_type(4)));
typedef int    i32x4  __attribute__((ext_vector_type(4)));
typedef int    i32x2  __attribute__((ext_vector_type(2)));
typedef unsigned short u16x4 __attribute__((ext_vector_type(4)));

// workspace layout (bytes)
#define Y_OFF     0u          // rows [N_CHILD][128B]: bf16 h, then int8 y8 in first 64B
#define S_OFF     67108864u   // f32 s[N_CHILD] per-row scales = 2097152
#define WTUP_OFF  69206016u   // bf16 WtUp [8][64 n][128 k] = 131072
#define W8CV_OFF  69337088u   // i8 Wt8 [27][64 n][64 j] = 110592
#define TINV_OFF  69447680u   // f32 Tinv[64] = 256
#define S1_OFF    69447936u   // f32 bins1 [64][128] = 32768
#define S2_OFF    69480704u   // f32 bins2 [64][128] = 32768
#define AB1_OFF   69513472u   // f32 a1[64], b1[64] = 512
#define AB2_OFF   69513984u   // f32 a2[64], b2[64] = 512

__device__ __forceinline__ float elu_f(float f) {
    return f > 0.f ? f : (__expf(f) - 1.f);
}

__device__ __forceinline__ void gload_lds16(const void* g, void* l) {
    __builtin_amdgcn_global_load_lds((const __attribute__((address_space(1))) void*)g,
                                     (__attribute__((address_space(3))) void*)l, 16, 0, 0);
}

// ---- prep_tc: per-output-column absmax of W_conv -> Tinv[c] = 127/max ----
// 64 blocks, one per column.
__global__ __launch_bounds__(256) void prep_tc(const float* __restrict__ wcv,
                                               float* __restrict__ tinv) {
    __shared__ float part[4];
    int c = blockIdx.x, t = threadIdx.x;
    float m = 0.f;
    for (int i = t; i < 1728; i += 256) m = fmaxf(m, fabsf(wcv[i * 64 + c]));
#pragma unroll
    for (int d = 1; d < 64; d <<= 1) m = fmaxf(m, __shfl_xor(m, d));
    if ((t & 63) == 0) part[t >> 6] = m;
    __syncthreads();
    if (t == 0) {
        float mm = fmaxf(fmaxf(part[0], part[1]), fmaxf(part[2], part[3]));
        tinv[c] = 127.f / fmaxf(mm, 1e-20f);
    }
}

// ---- prep: WtUp transpose->bf16; W_conv -> int8 [27][n][j] with Tinv[n] ----
__global__ __launch_bounds__(256) void prep_w(const float* __restrict__ wup,
                                              const float* __restrict__ wcv,
                                              __bf16* __restrict__ wtup,
                                              signed char* __restrict__ w8,
                                              const float* __restrict__ tinv) {
    int i = blockIdx.x * 256 + threadIdx.x;
    if (i < 8 * 64 * 128) {
        int o = i >> 13, rem = i & 8191, n = rem >> 7, k = rem & 127;
        wtup[i] = (__bf16)wup[o * 8192 + k * 64 + n];
    } else {
        int j2 = i - 65536;                   // j2 < 27*64*64 = 110592
        int t = j2 >> 12, rem = j2 & 4095, n = rem >> 6, j = rem & 63;
        float v = wcv[(t * 64 + j) * 64 + n] * tinv[n];
        w8[j2] = (signed char)(int)rintf(v);
    }
}

// ---- kernel A: h[8p+oct] = x[p] @ W_up[oct] (bf16), accumulate BN1 stats ----
__global__ __launch_bounds__(256) void deconv_bn_stats(
    const float* __restrict__ x, const __bf16* __restrict__ wtup,
    __bf16* __restrict__ y, float* __restrict__ bins) {
    __shared__ float ssum[64], ssq[64];
    int tid = threadIdx.x;
    int wave = tid >> 6, lane = tid & 63, lr = lane & 15, lg = lane >> 4;
    int p0 = blockIdx.x * 16;

    if (tid < 64) { ssum[tid] = 0.f; ssq[tid] = 0.f; }

    const float* xrow = x + (size_t)(p0 + lr) * C_IN;
    bf16x8 afr[4];
#pragma unroll
    for (int ks = 0; ks < 4; ++ks) {
        const float* src = xrow + ks * 32 + lg * 8;
        f32x4 u0 = *(const f32x4*)(src);
        f32x4 u1 = *(const f32x4*)(src + 4);
        bf16x8 a;
#pragma unroll
        for (int i = 0; i < 4; ++i) { a[i] = (__bf16)u0[i]; a[4 + i] = (__bf16)u1[i]; }
        afr[ks] = a;
    }

    float lsum[4] = {0.f, 0.f, 0.f, 0.f}, lsq[4] = {0.f, 0.f, 0.f, 0.f};
#pragma unroll
    for (int oo = 0; oo < 2; ++oo) {
        int oct = wave * 2 + oo;
#pragma unroll
        for (int nt = 0; nt < 4; ++nt) {
            f32x4 acc = {0.f, 0.f, 0.f, 0.f};
#pragma unroll
            for (int ks = 0; ks < 4; ++ks) {
                const __bf16* bp = wtup + ((size_t)(oct * 64 + nt * 16 + lr) * C_IN + ks * 32 + lg * 8);
                bf16x8 b = *(const bf16x8*)bp;
                acc = __builtin_amdgcn_mfma_f32_16x16x32_bf16(afr[ks], b, acc, 0, 0, 0);
            }
#pragma unroll
            for (int r = 0; r < 4; ++r) {
                int parent = p0 + lg * 4 + r;
                int child = parent * 8 + oct;
                float v = acc[r];
                y[(size_t)child * 64 + nt * 16 + lr] = (__bf16)v;
                lsum[nt] += v; lsq[nt] += v * v;
            }
        }
    }
    __syncthreads();
#pragma unroll
    for (int nt = 0; nt < 4; ++nt) {
        atomicAdd(&ssum[nt * 16 + lr], lsum[nt]);
        atomicAdd(&ssq[nt * 16 + lr], lsq[nt]);
    }
    __syncthreads();
    if (tid < 64) {
        float* b = bins + (size_t)(blockIdx.x & (NBINS - 1)) * 128;
        atomicAdd(&b[tid], ssum[tid]);
        atomicAdd(&b[64 + tid], ssq[tid]);
    }
}

// ---- finalize: per-channel a = gamma*rstd, b = beta - mu*a ----
__global__ void finalize_stats(const float* __restrict__ bins,
                               const float* __restrict__ gamma,
                               const float* __restrict__ beta,
                               float* __restrict__ ab, float invN) {
    int c = threadIdx.x;  // 64 threads
    float s = 0.f, q = 0.f;
    for (int b = 0; b < NBINS; ++b) { s += bins[b * 128 + c]; q += bins[b * 128 + 64 + c]; }
    float mu = s * invN;
    float var = q * invN - mu * mu;
    float rstd = rsqrtf(var + 1e-5f);
    float a = gamma[c] * rstd;
    ab[c] = a;
    ab[64 + c] = beta[c] - mu * a;
}

// ---- BN1 + ELU + per-row int8 quant, in place (8 threads per row) ----
__global__ __launch_bounds__(256) void bn_elu_quant(char* __restrict__ ybuf,
                                                    float* __restrict__ sArr,
                                                    const float* __restrict__ ab) {
    int gt = blockIdx.x * 256 + threadIdx.x;
    int row = gt >> 3, tc = gt & 7;
    int c0 = tc * 8;
    const __bf16* yr = (const __bf16*)(ybuf + (size_t)row * 128);
    bf16x8 h = *(const bf16x8*)(yr + c0);
    float v[8];
    float m = 0.f;
#pragma unroll
    for (int j = 0; j < 8; ++j) {
        float f = (float)h[j] * ab[c0 + j] + ab[64 + c0 + j];
        f = elu_f(f);
        v[j] = f;
        m = fmaxf(m, fabsf(f));
    }
    m = fmaxf(m, __shfl_xor(m, 1));
    m = fmaxf(m, __shfl_xor(m, 2));
    m = fmaxf(m, __shfl_xor(m, 4));
    m = fmaxf(m, 1e-6f);
    float inv = 127.f / m;
    int lo = 0, hi = 0;
#pragma unroll
    for (int j = 0; j < 4; ++j) {
        int q0 = (int)rintf(v[j] * inv);
        int q1 = (int)rintf(v[4 + j] * inv);
        lo |= (q0 & 255) << (8 * j);
        hi |= (q1 & 255) << (8 * j);
    }
    i32x2 pk; pk[0] = lo; pk[1] = hi;
    *(i32x2*)(ybuf + (size_t)row * 128 + tc * 8) = pk;
    if (tc == 0) sArr[row] = m * (1.f / 127.f);
}

// ---- kernel C: 27-tap gather conv, 2-deep pipeline, counted vmcnt ----
// 256 thr = 4 waves; wave owns 32 rows x 64 cols. VMEM queue per tap:
// 2 gathers (G) + 4 B-loads, issued 2 taps ahead; steady wait = vmcnt(6).
__global__ __launch_bounds__(256, 4) void conv_bn_stats(
    const char* __restrict__ ybuf, const int* __restrict__ neigh,
    const signed char* __restrict__ w8, const float* __restrict__ sArr,
    float* __restrict__ out, float* __restrict__ bins) {
    __shared__ __align__(16) char tiles[4][2][2048];
    __shared__ __align__(16) int idxb_s[4][32 * TAPS];
    __shared__ __align__(16) unsigned short scl_s[4][32 * TAPS];
    __shared__ float ssum[64], ssq[64];
    int tid = threadIdx.x;
    int wave = tid >> 6, lane = tid & 63, lr = lane & 15, lg = lane >> 4;
    int wr0 = blockIdx.x * 128 + wave * 32;

    if (tid < 64) { ssum[tid] = 0.f; ssq[tid] = 0.f; }

    char* tile0 = tiles[wave][0];
    char* tile1 = tiles[wave][1];
    int*  idxb  = idxb_s[wave];
    unsigned short* scl = scl_s[wave];

    // gather source swizzle: LDS slot s of tile-row r holds global chunk (s-(r>>1))&3
    int srcoff = (((lane & 3) + 4 - ((lane >> 2) >> 1)) & 3) * 16;
    int i0 = lane >> 2;
    int chunk = (lg + (lr >> 1)) & 3;
    int aoff0 = lr * 64 + chunk * 16;
    int aoff1 = 1024 + lr * 64 + chunk * 16;

    // ---- stage neighbor indices into LDS ----
    {
        int base_w = wr0 * TAPS;
#pragma unroll
        for (int j = 0; j < 14; ++j) {
            int w = j * 64 + lane;
            if (w < 32 * TAPS) idxb[w] = neigh[base_w + w];
        }
    }
    asm volatile("s_waitcnt vmcnt(0) lgkmcnt(0)" ::: "memory");
    __builtin_amdgcn_sched_barrier(0);
    // ---- stage per-row scales (bf16) ----
    if (lane < 32) {
#pragma unroll
        for (int k = 0; k < TAPS; ++k) {
            float s = sArr[idxb[lane * TAPS + k]];
            __bf16 b = (__bf16)s;
            scl[k * 32 + lane] = *(unsigned short*)&b;
        }
    }
    asm volatile("s_waitcnt vmcnt(0) lgkmcnt(0)" ::: "memory");
    __builtin_amdgcn_sched_barrier(0);

    f32x4 facc[2][4];
#pragma unroll
    for (int mt = 0; mt < 2; ++mt)
#pragma unroll
        for (int nt = 0; nt < 4; ++nt) facc[mt][nt] = (f32x4){0.f, 0.f, 0.f, 0.f};

    const signed char* w8l = w8 + lr * 64 + lg * 16;

    // ---- prologue: issue B(0),B(1),G(0),G(1) — queue = [B0x4,B1x4,G0x2,G1x2]
    i32x4 bfr[2][4];
#pragma unroll
    for (int nt = 0; nt < 4; ++nt) bfr[0][nt] = *(const i32x4*)(w8l + nt * 1024);
#pragma unroll
    for (int nt = 0; nt < 4; ++nt) bfr[1][nt] = *(const i32x4*)(w8l + 4096 + nt * 1024);
    {
        int g00 = idxb[i0 * TAPS + 0], g01 = idxb[(i0 + 16) * TAPS + 0];
        int g10 = idxb[i0 * TAPS + 1], g11 = idxb[(i0 + 16) * TAPS + 1];
        gload_lds16(ybuf + (size_t)(unsigned)g00 * 128 + srcoff, tile0);
        gload_lds16(ybuf + (size_t)(unsigned)g01 * 128 + srcoff, tile0 + 1024);
        gload_lds16(ybuf + (size_t)(unsigned)g10 * 128 + srcoff, tile1);
        gload_lds16(ybuf + (size_t)(unsigned)g11 * 128 + srcoff, tile1 + 1024);
    }

#pragma unroll
    for (int k = 0; k < TAPS; ++k) {
        char* tk = (k & 1) ? tile1 : tile0;
        // wait: need G(k)+B(k) done; leave next tap's G/B in flight
        if (k == 0)       { asm volatile("s_waitcnt vmcnt(2)" ::: "memory"); }
        else if (k == 26) { asm volatile("s_waitcnt vmcnt(0)" ::: "memory"); }
        else              { asm volatile("s_waitcnt vmcnt(6)" ::: "memory"); }
        __builtin_amdgcn_sched_barrier(0);
        // LDS reads: A fragments, scales, next-next tap indices
        i32x4 a0 = *(const i32x4*)(tk + aoff0);
        i32x4 a1 = *(const i32x4*)(tk + aoff1);
        u16x4 u0 = *(const u16x4*)(scl + k * 32 + lg * 4);
        u16x4 u1 = *(const u16x4*)(scl + k * 32 + 16 + lg * 4);
        int gi0 = 0, gi1 = 0;
        if (k + 2 < TAPS) {
            gi0 = idxb[i0 * TAPS + (k + 2)];
            gi1 = idxb[(i0 + 16) * TAPS + (k + 2)];
        }
        asm volatile("s_waitcnt lgkmcnt(0)" ::: "memory");
        __builtin_amdgcn_sched_barrier(0);
        // issue G(k+2) into the tile just consumed (WAR-safe: lgkm drained)
        if (k + 2 < TAPS) {
            gload_lds16(ybuf + (size_t)(unsigned)gi0 * 128 + srcoff, tk);
            gload_lds16(ybuf + (size_t)(unsigned)gi1 * 128 + srcoff, tk + 1024);
        }
        // dequant scales
        f32x4 sv0, sv1;
#pragma unroll
        for (int j = 0; j < 4; ++j) {
            sv0[j] = __uint_as_float((unsigned)u0[j] << 16);
            sv1[j] = __uint_as_float((unsigned)u1[j] << 16);
        }
        // MFMAs + scale-accumulate (uses bfr[k&1])
#pragma unroll
        for (int nt = 0; nt < 4; ++nt) {
            i32x4 q0 = __builtin_amdgcn_mfma_i32_16x16x64_i8(a0, bfr[k & 1][nt], (i32x4){0,0,0,0}, 0, 0, 0);
            i32x4 q1 = __builtin_amdgcn_mfma_i32_16x16x64_i8(a1, bfr[k & 1][nt], (i32x4){0,0,0,0}, 0, 0, 0);
#pragma unroll
            for (int j = 0; j < 4; ++j) {
                facc[0][nt][j] += sv0[j] * (float)q0[j];
                facc[1][nt][j] += sv1[j] * (float)q1[j];
            }
        }
        // issue B(k+2) into bfr[k&1] (regs just freed by the MFMAs above)
        if (k + 2 < TAPS) {
#pragma unroll
            for (int nt = 0; nt < 4; ++nt)
                bfr[k & 1][nt] = *(const i32x4*)(w8l + (k + 2) * 4096 + nt * 1024);
        }
    }

    float lsum[4] = {0.f, 0.f, 0.f, 0.f}, lsq[4] = {0.f, 0.f, 0.f, 0.f};
#pragma unroll
    for (int mt = 0; mt < 2; ++mt)
#pragma unroll
        for (int nt = 0; nt < 4; ++nt)
#pragma unroll
            for (int r = 0; r < 4; ++r) {
                float v = facc[mt][nt][r];
                int row = wr0 + mt * 16 + lg * 4 + r;
                out[(size_t)row * C_OUT + nt * 16 + lr] = v;
                lsum[nt] += v; lsq[nt] += v * v;
            }
    __syncthreads();
#pragma unroll
    for (int nt = 0; nt < 4; ++nt) {
        atomicAdd(&ssum[nt * 16 + lr], lsum[nt]);
        atomicAdd(&ssq[nt * 16 + lr], lsq[nt]);
    }
    __syncthreads();
    if (tid < 64) {
        float* b = bins + (size_t)(blockIdx.x & (NBINS - 1)) * 128;
        atomicAdd(&b[tid], ssum[tid]);
        atomicAdd(&b[64 + tid], ssq[tid]);
    }
}

// ---- BN2 + ELU applied in place on f32 d_out ----
__global__ __launch_bounds__(256) void bn_elu_out(float* __restrict__ out,
                                                  const float* __restrict__ ab) {
    int tid = blockIdx.x * 256 + threadIdx.x;
    int c0 = (tid * 4) & 63;
    float av[4], bv[4];
#pragma unroll
    for (int j = 0; j < 4; ++j) { av[j] = ab[c0 + j]; bv[j] = ab[64 + c0 + j]; }
#pragma unroll
    for (int t = 0; t < 8; ++t) {
        size_t e = ((size_t)t * 1048576 + tid) * 4;
        f32x4 v = *(const f32x4*)(out + e);
        f32x4 o;
#pragma unroll
        for (int j = 0; j < 4; ++j) o[j] = elu_f(v[j] * av[j] + bv[j]);
        *(f32x4*)(out + e) = o;
    }
}

extern "C" void kernel_launch(void* const* d_in, const int* in_sizes, int n_in,
                              void* d_out, int out_size, void* d_ws, size_t ws_size,
                              hipStream_t stream) {
    const float* x     = (const float*)d_in[0];
    const int*   neigh = (const int*)d_in[1];
    const float* wup   = (const float*)d_in[2];
    const float* wcv   = (const float*)d_in[3];
    const float* g1    = (const float*)d_in[4];
    const float* b1    = (const float*)d_in[5];
    const float* g2    = (const float*)d_in[6];
    const float* b2    = (const float*)d_in[7];
    float* out = (float*)d_out;

    char* ws = (char*)d_ws;
    char*        ybuf  = ws + Y_OFF;
    float*       sArr  = (float*)(ws + S_OFF);
    __bf16*      wtup  = (__bf16*)(ws + WTUP_OFF);
    signed char* w8    = (signed char*)(ws + W8CV_OFF);
    float*       tinv  = (float*)(ws + TINV_OFF);
    float*       bins1 = (float*)(ws + S1_OFF);
    float*       bins2 = (float*)(ws + S2_OFF);
    float*       ab1   = (float*)(ws + AB1_OFF);
    float*       ab2   = (float*)(ws + AB2_OFF);

    hipMemsetAsync(ws + S1_OFF, 0, 32768u * 2 + 1024u, stream);

    prep_tc<<<64, 256, 0, stream>>>(wcv, tinv);
    prep_w<<<688, 256, 0, stream>>>(wup, wcv, wtup, w8, tinv);
    deconv_bn_stats<<<N_PARENT / 16, 256, 0, stream>>>(x, wtup, (__bf16*)ybuf, bins1);
    finalize_stats<<<1, 64, 0, stream>>>(bins1, g1, b1, ab1, 1.f / (float)N_CHILD);
    bn_elu_quant<<<16384, 256, 0, stream>>>(ybuf, sArr, ab1);
    conv_bn_stats<<<N_CHILD / 128, 256, 0, stream>>>(ybuf, neigh, w8, sArr, out, bins2);
    finalize_stats<<<1, 64, 0, stream>>>(bins2, g2, b2, ab2, 1.f / (float)N_CHILD);
    bn_elu_out<<<4096, 256, 0, stream>>>(out, ab2);
}